// Round 7
// baseline (3031.542 us; speedup 1.0000x reference)
//
#include <hip/hip_runtime.h>

#define ASTR 68    // LDS tile row stride (floats): 16B-aligned, odd bank-quad
#define SSTR 129   // sims dump row stride

__device__ __forceinline__ unsigned long long pack_key(float s, int col) {
    unsigned u = __float_as_uint(s);
    unsigned m = (u & 0x80000000u) ? ~u : (u | 0x80000000u);
    return ((unsigned long long)m << 32) | (unsigned)(127 - col);
}
__device__ __forceinline__ float key_val(unsigned long long k) {
    unsigned m = (unsigned)(k >> 32);
    unsigned u = (m & 0x80000000u) ? (m ^ 0x80000000u) : ~m;
    return __uint_as_float(u);
}
__device__ __forceinline__ int key_col(unsigned long long k) {
    return 127 - (int)(k & 0xFFFFFFFFu);
}
__device__ __forceinline__ void ins3(unsigned long long x,
        unsigned long long &a0, unsigned long long &a1, unsigned long long &a2) {
    if (x > a0)      { a2 = a1; a1 = a0; a0 = x; }
    else if (x > a1) { a2 = a1; a1 = x; }
    else if (x > a2) { a2 = x; }
}

// codebook row norms, f64 accumulation — verbatim (validated)
__global__ void rn_kernel(const float* __restrict__ cb, float* __restrict__ rn) {
    const int j = blockIdx.x;
    const int t = threadIdx.x;
    double a = 0.0;
#pragma unroll
    for (int m = 0; m < 8; ++m) {
        float f = cb[j * 512 + m * 64 + t];
        a += (double)f * (double)f;
    }
#pragma unroll
    for (int off = 32; off >= 1; off >>= 1)
        a += __shfl_down(a, off);
    if (t == 0) rn[j] = (float)sqrt(a);
}

// Kernel A: xe = x @ W^T + b   (128x128 tile, 8x8 per thread, VGPR-cap 256)
// xe[r][c] stored at out[r*1536 + c]  (tt=0 slot of adapted region, block-local)
__global__ __launch_bounds__(256, 1) void xe_kernel(
    const float* __restrict__ x, const float* __restrict__ W,
    const float* __restrict__ bias, float* xe)
{
    __shared__ __align__(16) float xT[128 * ASTR];
    __shared__ __align__(16) float wT[128 * ASTR];

    const int tid  = threadIdx.x;
    const int rowg = tid >> 4;          // 0..15
    const int colg = tid & 15;          // 0..15
    const int col0 = blockIdx.x << 7;   // fast-varying: 4 col-tiles share x rows via L3
    const int row0 = blockIdx.y << 7;

    const int sr = tid >> 1;            // staging row 0..127
    const int sc = (tid & 1) << 5;      // 0 or 32
    const float* gx0 = x + (size_t)(row0 + sr) * 512 + sc;
    const float* gw0 = W + (size_t)(col0 + sr) * 512 + sc;
    float4* dx = (float4*)&xT[sr * ASTR + sc];
    float4* dw = (float4*)&wT[sr * ASTR + sc];

    float m1[8][8];
#pragma unroll
    for (int i = 0; i < 8; ++i)
#pragma unroll
        for (int j = 0; j < 8; ++j) m1[i][j] = 0.f;

    for (int kc = 0; kc < 8; ++kc) {
        {
            const float4* gx = (const float4*)(gx0 + kc * 64);
            const float4* gw = (const float4*)(gw0 + kc * 64);
            float4 rx[8], rw[8];
#pragma unroll
            for (int m = 0; m < 8; ++m) { rx[m] = gx[m]; rw[m] = gw[m]; }
            __syncthreads();             // prev compute done reading LDS
#pragma unroll
            for (int m = 0; m < 8; ++m) { dx[m] = rx[m]; dw[m] = rw[m]; }
        }
        __syncthreads();

        float s1[8][8];                  // per-64-chunk sub-accumulator (bit-exact scheme)
#pragma unroll
        for (int i = 0; i < 8; ++i)
#pragma unroll
            for (int j = 0; j < 8; ++j) s1[i][j] = 0.f;
#pragma unroll
        for (int kk = 0; kk < 16; ++kk) {
            float4 wa[8];
#pragma unroll
            for (int j = 0; j < 8; ++j)
                wa[j] = *(const float4*)&wT[(colg + 16 * j) * ASTR + (kk << 2)];
#pragma unroll
            for (int i = 0; i < 8; ++i) {
                const float4 xa = *(const float4*)&xT[(rowg + 16 * i) * ASTR + (kk << 2)];
#pragma unroll
                for (int j = 0; j < 8; ++j) {
                    s1[i][j] = fmaf(xa.x, wa[j].x, s1[i][j]);
                    s1[i][j] = fmaf(xa.y, wa[j].y, s1[i][j]);
                    s1[i][j] = fmaf(xa.z, wa[j].z, s1[i][j]);
                    s1[i][j] = fmaf(xa.w, wa[j].w, s1[i][j]);
                }
            }
        }
#pragma unroll
        for (int i = 0; i < 8; ++i)
#pragma unroll
            for (int j = 0; j < 8; ++j) m1[i][j] += s1[i][j];
    }
    // bias + store xe (f32, same fl(m1+bj) bits)
#pragma unroll
    for (int j = 0; j < 8; ++j) {
        const float bj = bias[col0 + colg + 16 * j];
#pragma unroll
        for (int i = 0; i < 8; ++i)
            xe[(size_t)(row0 + rowg + 16 * i) * 1536 + col0 + colg + 16 * j] = m1[i][j] + bj;
    }
}

// Kernel B: norms + sims + top3 + epilogue  (128 rows/block, 8x8 sims blocking)
__global__ __launch_bounds__(256, 1) void sims_kernel(
    const float* __restrict__ cb, const float* __restrict__ u,
    const float* __restrict__ v, const float* __restrict__ rn,
    float* out, size_t idx_off, size_t val_off)
{
    __shared__ __align__(16) float shB[2 * 128 * ASTR];   // eT | cT, reused as sims dump
    __shared__ float rnL[128];
    __shared__ float xnL[128];
    __shared__ unsigned char idxL[128 * 3];

    float* eT = shB;
    float* cT = shB + 128 * ASTR;

    const int tid  = threadIdx.x;
    const int rowg = tid >> 4;
    const int colg = tid & 15;
    const int row0 = blockIdx.x << 7;

    if (tid < 128) rnL[tid] = rn[tid];

    const int sr = tid >> 1;
    const int sc = (tid & 1) << 5;
    const float* ge0 = out + (size_t)(row0 + sr) * 1536 + sc;   // xe rows
    const float* gc0 = cb + (size_t)sr * 512 + sc;
    float4* de = (float4*)&eT[sr * ASTR + sc];
    float4* dc = (float4*)&cT[sr * ASTR + sc];

    float m2[8][8];
#pragma unroll
    for (int i = 0; i < 8; ++i)
#pragma unroll
        for (int j = 0; j < 8; ++j) m2[i][j] = 0.f;
    float nacc = 0.f;

    for (int dc2 = 0; dc2 < 8; ++dc2) {
        {
            const float4* ge = (const float4*)(ge0 + dc2 * 64);
            const float4* gc = (const float4*)(gc0 + dc2 * 64);
            float4 re[8], rc[8];
#pragma unroll
            for (int m = 0; m < 8; ++m) { re[m] = ge[m]; rc[m] = gc[m]; }
            __syncthreads();
#pragma unroll
            for (int m = 0; m < 8; ++m) { de[m] = re[m]; dc[m] = rc[m]; }
        }
        __syncthreads();

        // norm chain (rows 0..127, d-ascending, exact validated order)
        if (tid < 128) {
#pragma unroll
            for (int dd = 0; dd < 16; ++dd) {
                float4 q = *(const float4*)&eT[tid * ASTR + (dd << 2)];
                nacc = fmaf(q.x, q.x, nacc);
                nacc = fmaf(q.y, q.y, nacc);
                nacc = fmaf(q.z, q.z, nacc);
                nacc = fmaf(q.w, q.w, nacc);
            }
        }
        // sims partial over this 64-d chunk
        float s2[8][8];
#pragma unroll
        for (int i = 0; i < 8; ++i)
#pragma unroll
            for (int j = 0; j < 8; ++j) s2[i][j] = 0.f;
#pragma unroll
        for (int dd = 0; dd < 16; ++dd) {
            float4 rv[8];
#pragma unroll
            for (int j = 0; j < 8; ++j)
                rv[j] = *(const float4*)&cT[(colg + 16 * j) * ASTR + (dd << 2)];
#pragma unroll
            for (int i = 0; i < 8; ++i) {
                const float4 xv = *(const float4*)&eT[(rowg + 16 * i) * ASTR + (dd << 2)];
#pragma unroll
                for (int j = 0; j < 8; ++j) {
                    s2[i][j] = fmaf(xv.x, rv[j].x, s2[i][j]);
                    s2[i][j] = fmaf(xv.y, rv[j].y, s2[i][j]);
                    s2[i][j] = fmaf(xv.z, rv[j].z, s2[i][j]);
                    s2[i][j] = fmaf(xv.w, rv[j].w, s2[i][j]);
                }
            }
        }
#pragma unroll
        for (int i = 0; i < 8; ++i)
#pragma unroll
            for (int j = 0; j < 8; ++j) m2[i][j] += s2[i][j];
    }
    __syncthreads();                     // all eT/cT reads done
    // dump sims numerators
#pragma unroll
    for (int i = 0; i < 8; ++i)
#pragma unroll
        for (int j = 0; j < 8; ++j)
            shB[(rowg + 16 * i) * SSTR + colg + 16 * j] = m2[i][j];
    if (tid < 128) xnL[tid] = sqrtf(nacc);
    __syncthreads();

    // top-3: 2 threads/row, packed keys (order-independent, exact tie semantics)
    {
        const int row = tid >> 1;
        const int p   = tid & 1;
        const float xn = xnL[row];
        unsigned long long a0 = 0, a1 = 0, a2 = 0;
#pragma unroll
        for (int t = 0; t < 64; ++t) {
            const int c = p + 2 * t;
            float s = shB[row * SSTR + c] / fmaxf(xn * rnL[c], 1e-8f);
            ins3(pack_key(s, c), a0, a1, a2);
        }
        {
            unsigned long long b0 = __shfl_xor(a0, 1);
            unsigned long long b1 = __shfl_xor(a1, 1);
            unsigned long long b2 = __shfl_xor(a2, 1);
            ins3(b0, a0, a1, a2); ins3(b1, a0, a1, a2); ins3(b2, a0, a1, a2);
        }
        if (p == 0) {
            const size_t g = (size_t)(row0 + row);
            float* oi = out + idx_off + g * 3;
            float* ov = out + val_off + g * 3;
            oi[0] = (float)key_col(a0); oi[1] = (float)key_col(a1); oi[2] = (float)key_col(a2);
            ov[0] = key_val(a0); ov[1] = key_val(a1); ov[2] = key_val(a2);
            idxL[row * 3 + 0] = (unsigned char)key_col(a0);
            idxL[row * 3 + 1] = (unsigned char)key_col(a1);
            idxL[row * 3 + 2] = (unsigned char)key_col(a2);
        }
    }
    __syncthreads();

    // adapted_centers = cb[idx] + u[tt]*v   (1536 tasks over 256 threads)
    const float uu0 = u[0], uu1 = u[1], uu2 = u[2];
#pragma unroll
    for (int q = 0; q < 6; ++q) {
        int task = tid + 256 * q;            // 128 rows * 3 tt * 4 seg
        int row = task / 12;
        int rem = task - row * 12;
        int tt  = rem >> 2;
        int seg = rem & 3;
        int idx = idxL[row * 3 + tt];
        float uu = (tt == 0) ? uu0 : ((tt == 1) ? uu1 : uu2);
        const float4* gr4 = (const float4*)(cb + (size_t)idx * 512 + seg * 128);
        const float4* gv4 = (const float4*)(v + seg * 128);
        float4* ob = (float4*)(out + ((size_t)(row0 + row) * 3 + tt) * 512 + seg * 128);
#pragma unroll
        for (int c2 = 0; c2 < 32; ++c2) {
            float4 rv = gr4[c2];
            float4 vv = gv4[c2];
            float4 o;
            o.x = fmaf(uu, vv.x, rv.x);
            o.y = fmaf(uu, vv.y, rv.y);
            o.z = fmaf(uu, vv.z, rv.z);
            o.w = fmaf(uu, vv.w, rv.w);
            ob[c2] = o;
        }
    }
}

extern "C" void kernel_launch(void* const* d_in, const int* in_sizes, int n_in,
                              void* d_out, int out_size, void* d_ws, size_t ws_size,
                              hipStream_t stream) {
    const float* x  = (const float*)d_in[0];
    const float* cb = (const float*)d_in[1];
    const float* W  = (const float*)d_in[2];
    const float* b  = (const float*)d_in[3];
    const float* u  = (const float*)d_in[4];
    const float* v  = (const float*)d_in[5];
    float* rn  = (float*)d_ws;                       // 128 floats scratch
    float* out = (float*)d_out;

    const size_t B = (size_t)in_sizes[0] / 512;      // 131072
    const size_t val_off = (size_t)out_size - 3 * B; // top_k_values
    const size_t idx_off = (size_t)out_size - 6 * B; // top_k_indices

    hipLaunchKernelGGL(rn_kernel, dim3(128), dim3(64), 0, stream, cb, rn);
    hipLaunchKernelGGL(xe_kernel, dim3(4, (unsigned)(B / 128)), dim3(256), 0, stream,
                       x, W, b, out);
    hipLaunchKernelGGL(sims_kernel, dim3((unsigned)(B / 128)), dim3(256), 0, stream,
                       cb, u, v, rn, out, idx_off, val_off);
}

// Round 8
// 2434.873 us; speedup vs baseline: 1.2451x; 1.2451x over previous
//
#include <hip/hip_runtime.h>

#define ASTR 68     // LDS tile row stride (floats): 16B-aligned, odd bank-quad
#define SSTR4 132   // topk sims LDS row stride (16B-aligned)

__device__ __forceinline__ unsigned long long pack_key(float s, int col) {
    unsigned u = __float_as_uint(s);
    unsigned m = (u & 0x80000000u) ? ~u : (u | 0x80000000u);
    return ((unsigned long long)m << 32) | (unsigned)(127 - col);
}
__device__ __forceinline__ float key_val(unsigned long long k) {
    unsigned m = (unsigned)(k >> 32);
    unsigned u = (m & 0x80000000u) ? (m ^ 0x80000000u) : ~m;
    return __uint_as_float(u);
}
__device__ __forceinline__ int key_col(unsigned long long k) {
    return 127 - (int)(k & 0xFFFFFFFFu);
}
__device__ __forceinline__ void ins3(unsigned long long x,
        unsigned long long &a0, unsigned long long &a1, unsigned long long &a2) {
    if (x > a0)      { a2 = a1; a1 = a0; a0 = x; }
    else if (x > a1) { a2 = a1; a1 = x; }
    else if (x > a2) { a2 = x; }
}

// K1: codebook row norms, f64 accumulation — verbatim (validated)
__global__ void rn_kernel(const float* __restrict__ cb, float* __restrict__ rn) {
    const int j = blockIdx.x;
    const int t = threadIdx.x;
    double a = 0.0;
#pragma unroll
    for (int m = 0; m < 8; ++m) {
        float f = cb[j * 512 + m * 64 + t];
        a += (double)f * (double)f;
    }
#pragma unroll
    for (int off = 32; off >= 1; off >>= 1)
        a += __shfl_down(a, off);
    if (t == 0) rn[j] = (float)sqrt(a);
}

// K2: xe = x @ W^T + b.  Tile 128 rows x 64 cols, per-thread 8x4 (regs ~100).
// xe[r][c] -> out[r*1536 + c] (tt=0 slot, block-local, overwritten by epilogue later)
__global__ __launch_bounds__(256, 2) void xe_kernel(
    const float* __restrict__ x, const float* __restrict__ W,
    const float* __restrict__ bias, float* __restrict__ out)
{
    __shared__ __align__(16) float xT[128 * ASTR];
    __shared__ __align__(16) float wT[64 * ASTR];

    const int tid  = threadIdx.x;
    const int rowg = tid >> 4;          // 0..15
    const int colg = tid & 15;          // 0..15
    const int col0 = blockIdx.x << 6;   // fast-varying: 8 col-tiles share x panel via L3
    const int row0 = blockIdx.y << 7;

    const int xr = tid >> 1;            // xT staging: 128 rows, 32 floats each
    const int xc = (tid & 1) << 5;
    const int wr = tid >> 2;            // wT staging: 64 rows, 16 floats each
    const int wc = (tid & 3) << 4;
    const float* gx0 = x + (size_t)(row0 + xr) * 512 + xc;
    const float* gw0 = W + (size_t)(col0 + wr) * 512 + wc;
    float4* dx = (float4*)&xT[xr * ASTR + xc];
    float4* dw = (float4*)&wT[wr * ASTR + wc];

    float m1[8][4];
#pragma unroll
    for (int i = 0; i < 8; ++i)
#pragma unroll
        for (int j = 0; j < 4; ++j) m1[i][j] = 0.f;

    for (int kc = 0; kc < 8; ++kc) {
        {
            const float4* gx = (const float4*)(gx0 + kc * 64);
            const float4* gw = (const float4*)(gw0 + kc * 64);
            float4 rx[8], rw[4];
#pragma unroll
            for (int m = 0; m < 8; ++m) rx[m] = gx[m];
#pragma unroll
            for (int m = 0; m < 4; ++m) rw[m] = gw[m];
            __syncthreads();             // prev compute done reading LDS
#pragma unroll
            for (int m = 0; m < 8; ++m) dx[m] = rx[m];
#pragma unroll
            for (int m = 0; m < 4; ++m) dw[m] = rw[m];
        }
        __syncthreads();

        float s1[8][4];                  // per-64-chunk sub-accumulator (validated chain)
#pragma unroll
        for (int i = 0; i < 8; ++i)
#pragma unroll
            for (int j = 0; j < 4; ++j) s1[i][j] = 0.f;
#pragma unroll
        for (int kk = 0; kk < 16; ++kk) {
            float4 wa[4];
#pragma unroll
            for (int j = 0; j < 4; ++j)
                wa[j] = *(const float4*)&wT[(colg + 16 * j) * ASTR + (kk << 2)];
#pragma unroll
            for (int i = 0; i < 8; ++i) {
                const float4 xa = *(const float4*)&xT[(rowg + 16 * i) * ASTR + (kk << 2)];
#pragma unroll
                for (int j = 0; j < 4; ++j) {
                    s1[i][j] = fmaf(xa.x, wa[j].x, s1[i][j]);
                    s1[i][j] = fmaf(xa.y, wa[j].y, s1[i][j]);
                    s1[i][j] = fmaf(xa.z, wa[j].z, s1[i][j]);
                    s1[i][j] = fmaf(xa.w, wa[j].w, s1[i][j]);
                }
            }
        }
#pragma unroll
        for (int i = 0; i < 8; ++i)
#pragma unroll
            for (int j = 0; j < 4; ++j) m1[i][j] += s1[i][j];
    }
    // bias + store xe (fl(m1+bj), same bits as validated)
#pragma unroll
    for (int j = 0; j < 4; ++j) {
        const float bj = bias[col0 + colg + 16 * j];
#pragma unroll
        for (int i = 0; i < 8; ++i)
            out[(size_t)(row0 + rowg + 16 * i) * 1536 + col0 + colg + 16 * j] = m1[i][j] + bj;
    }
}

// K3: sims numerators + row norms.  128 rows x 128 cb-cols via two 64-col halves,
// per-thread 8x4.  sims[r][c] -> out[r*1536 + 512 + c]; xn[r] -> out[r*1536 + 1024].
__global__ __launch_bounds__(256, 2) void sims_kernel(
    const float* __restrict__ cb, float* __restrict__ out)
{
    __shared__ __align__(16) float eT[128 * ASTR];
    __shared__ __align__(16) float cT[64 * ASTR];

    const int tid  = threadIdx.x;
    const int rowg = tid >> 4;
    const int colg = tid & 15;
    const int row0 = blockIdx.x << 7;

    const int er = tid >> 1;
    const int ec = (tid & 1) << 5;
    const int cr = tid >> 2;
    const int cc = (tid & 3) << 4;
    const float* ge0 = out + (size_t)(row0 + er) * 1536 + ec;   // xe rows
    float4* de = (float4*)&eT[er * ASTR + ec];
    float4* dcp = (float4*)&cT[cr * ASTR + cc];

    float nacc = 0.f;

    for (int ch = 0; ch < 2; ++ch) {
        const float* gc0 = cb + (size_t)(ch * 64 + cr) * 512 + cc;
        float m2[8][4];
#pragma unroll
        for (int i = 0; i < 8; ++i)
#pragma unroll
            for (int j = 0; j < 4; ++j) m2[i][j] = 0.f;

        for (int dc2 = 0; dc2 < 8; ++dc2) {
            {
                const float4* ge = (const float4*)(ge0 + dc2 * 64);
                const float4* gc = (const float4*)(gc0 + dc2 * 64);
                float4 re[8], rc[4];
#pragma unroll
                for (int m = 0; m < 8; ++m) re[m] = ge[m];
#pragma unroll
                for (int m = 0; m < 4; ++m) rc[m] = gc[m];
                __syncthreads();
#pragma unroll
                for (int m = 0; m < 8; ++m) de[m] = re[m];
#pragma unroll
                for (int m = 0; m < 4; ++m) dcp[m] = rc[m];
            }
            __syncthreads();

            // norm chain once (ch==0), d-ascending, exact validated order
            if (ch == 0 && tid < 128) {
#pragma unroll
                for (int dd = 0; dd < 16; ++dd) {
                    float4 q = *(const float4*)&eT[tid * ASTR + (dd << 2)];
                    nacc = fmaf(q.x, q.x, nacc);
                    nacc = fmaf(q.y, q.y, nacc);
                    nacc = fmaf(q.z, q.z, nacc);
                    nacc = fmaf(q.w, q.w, nacc);
                }
            }
            float s2[8][4];
#pragma unroll
            for (int i = 0; i < 8; ++i)
#pragma unroll
                for (int j = 0; j < 4; ++j) s2[i][j] = 0.f;
#pragma unroll
            for (int dd = 0; dd < 16; ++dd) {
                float4 rv[4];
#pragma unroll
                for (int j = 0; j < 4; ++j)
                    rv[j] = *(const float4*)&cT[(colg + 16 * j) * ASTR + (dd << 2)];
#pragma unroll
                for (int i = 0; i < 8; ++i) {
                    const float4 xv = *(const float4*)&eT[(rowg + 16 * i) * ASTR + (dd << 2)];
#pragma unroll
                    for (int j = 0; j < 4; ++j) {
                        s2[i][j] = fmaf(xv.x, rv[j].x, s2[i][j]);
                        s2[i][j] = fmaf(xv.y, rv[j].y, s2[i][j]);
                        s2[i][j] = fmaf(xv.z, rv[j].z, s2[i][j]);
                        s2[i][j] = fmaf(xv.w, rv[j].w, s2[i][j]);
                    }
                }
            }
#pragma unroll
            for (int i = 0; i < 8; ++i)
#pragma unroll
                for (int j = 0; j < 4; ++j) m2[i][j] += s2[i][j];
        }
        // dump this half's numerators (f32 bits exact)
#pragma unroll
        for (int j = 0; j < 4; ++j)
#pragma unroll
            for (int i = 0; i < 8; ++i)
                out[(size_t)(row0 + rowg + 16 * i) * 1536 + 512 + ch * 64 + colg + 16 * j] = m2[i][j];
    }
    if (tid < 128) out[(size_t)(row0 + tid) * 1536 + 1024] = sqrtf(nacc);
}

// K4: top-3 + epilogue (validated packed-key semantics; reads sims/xn bits from K3)
__global__ __launch_bounds__(256, 2) void topk_kernel(
    const float* __restrict__ cb, const float* __restrict__ u,
    const float* __restrict__ v, const float* __restrict__ rn,
    float* __restrict__ out, size_t idx_off, size_t val_off)
{
    __shared__ __align__(16) float simsL[128 * SSTR4];
    __shared__ float rnL[128];
    __shared__ float xnL[128];
    __shared__ unsigned char idxL[128 * 3];

    const int tid  = threadIdx.x;
    const int row0 = blockIdx.x << 7;

    if (tid < 128) {
        rnL[tid] = rn[tid];
        xnL[tid] = out[(size_t)(row0 + tid) * 1536 + 1024];
    }
    // stage sims tile [128][128] from global
    {
        const int sr = tid >> 1;
        const int hf = tid & 1;
        const float4* gs = (const float4*)(out + (size_t)(row0 + sr) * 1536 + 512 + hf * 64);
        float4* ds = (float4*)&simsL[sr * SSTR4 + hf * 64];
#pragma unroll
        for (int m = 0; m < 16; ++m) ds[m] = gs[m];
    }
    __syncthreads();

    // top-3: 2 threads/row, packed keys (exact tie semantics, validated)
    {
        const int row = tid >> 1;
        const int p   = tid & 1;
        const float xn = xnL[row];
        unsigned long long a0 = 0, a1 = 0, a2 = 0;
#pragma unroll
        for (int t = 0; t < 64; ++t) {
            const int c = p + 2 * t;
            float s = simsL[row * SSTR4 + c] / fmaxf(xn * rnL[c], 1e-8f);
            ins3(pack_key(s, c), a0, a1, a2);
        }
        {
            unsigned long long b0 = __shfl_xor(a0, 1);
            unsigned long long b1 = __shfl_xor(a1, 1);
            unsigned long long b2 = __shfl_xor(a2, 1);
            ins3(b0, a0, a1, a2); ins3(b1, a0, a1, a2); ins3(b2, a0, a1, a2);
        }
        if (p == 0) {
            const size_t g = (size_t)(row0 + row);
            float* oi = out + idx_off + g * 3;
            float* ov = out + val_off + g * 3;
            oi[0] = (float)key_col(a0); oi[1] = (float)key_col(a1); oi[2] = (float)key_col(a2);
            ov[0] = key_val(a0); ov[1] = key_val(a1); ov[2] = key_val(a2);
            idxL[row * 3 + 0] = (unsigned char)key_col(a0);
            idxL[row * 3 + 1] = (unsigned char)key_col(a1);
            idxL[row * 3 + 2] = (unsigned char)key_col(a2);
        }
    }
    __syncthreads();

    // adapted_centers = cb[idx] + u[tt]*v   (overwrites xe/sims/xn slots)
    const float uu0 = u[0], uu1 = u[1], uu2 = u[2];
#pragma unroll
    for (int q = 0; q < 6; ++q) {
        int task = tid + 256 * q;            // 128 rows * 3 tt * 4 seg
        int row = task / 12;
        int rem = task - row * 12;
        int tt  = rem >> 2;
        int seg = rem & 3;
        int idx = idxL[row * 3 + tt];
        float uu = (tt == 0) ? uu0 : ((tt == 1) ? uu1 : uu2);
        const float4* gr4 = (const float4*)(cb + (size_t)idx * 512 + seg * 128);
        const float4* gv4 = (const float4*)(v + seg * 128);
        float4* ob = (float4*)(out + ((size_t)(row0 + row) * 3 + tt) * 512 + seg * 128);
#pragma unroll
        for (int c2 = 0; c2 < 32; ++c2) {
            float4 rv = gr4[c2];
            float4 vv = gv4[c2];
            float4 o;
            o.x = fmaf(uu, vv.x, rv.x);
            o.y = fmaf(uu, vv.y, rv.y);
            o.z = fmaf(uu, vv.z, rv.z);
            o.w = fmaf(uu, vv.w, rv.w);
            ob[c2] = o;
        }
    }
}

extern "C" void kernel_launch(void* const* d_in, const int* in_sizes, int n_in,
                              void* d_out, int out_size, void* d_ws, size_t ws_size,
                              hipStream_t stream) {
    const float* x  = (const float*)d_in[0];
    const float* cb = (const float*)d_in[1];
    const float* W  = (const float*)d_in[2];
    const float* b  = (const float*)d_in[3];
    const float* u  = (const float*)d_in[4];
    const float* v  = (const float*)d_in[5];
    float* rn  = (float*)d_ws;                       // 128 floats scratch
    float* out = (float*)d_out;

    const size_t B = (size_t)in_sizes[0] / 512;      // 131072
    const size_t val_off = (size_t)out_size - 3 * B; // top_k_values
    const size_t idx_off = (size_t)out_size - 6 * B; // top_k_indices

    hipLaunchKernelGGL(rn_kernel, dim3(128), dim3(64), 0, stream, cb, rn);
    hipLaunchKernelGGL(xe_kernel, dim3(8, (unsigned)(B / 128)), dim3(256), 0, stream,
                       x, W, b, out);
    hipLaunchKernelGGL(sims_kernel, dim3((unsigned)(B / 128)), dim3(256), 0, stream,
                       cb, out);
    hipLaunchKernelGGL(topk_kernel, dim3((unsigned)(B / 128)), dim3(256), 0, stream,
                       cb, u, v, rn, out, idx_off, val_off);
}